// Round 2
// baseline (315.394 us; speedup 1.0000x reference)
//
#include <hip/hip_runtime.h>
#include <hip/hip_bf16.h>
#include <math.h>

typedef short bf16x8 __attribute__((ext_vector_type(8)));
typedef float f32x4 __attribute__((ext_vector_type(4)));

#define T_SEQ 2048
#define C_DIM 1024
#define H_HEADS 16
#define D_HEAD 64
#define BT 4096          // B*T
#define C3 3072
#define BH 32            // B*H

static __device__ inline unsigned short bf_bits(float f) {
    __hip_bfloat16 h = __float2bfloat16(f);
    unsigned short u;
    __builtin_memcpy(&u, &h, 2);
    return u;
}

static __device__ inline unsigned int pkbf(float a, float b) {
    return (unsigned int)bf_bits(a) | ((unsigned int)bf_bits(b) << 16);
}

// ---------------- cast f32 -> bf16, 4 elems/thread ----------------
__global__ void cast_f32_bf16(const float* __restrict__ in,
                              __hip_bfloat16* __restrict__ out, int n4) {
    int i = blockIdx.x * blockDim.x + threadIdx.x;
    if (i >= n4) return;
    float4 v = reinterpret_cast<const float4*>(in)[i];
    ushort4 o;
    o.x = bf_bits(v.x); o.y = bf_bits(v.y); o.z = bf_bits(v.z); o.w = bf_bits(v.w);
    reinterpret_cast<ushort4*>(out)[i] = o;
}

// ---------------- GEMM: Cout = A(M,K) * Bw(N,K)^T, bf16 MFMA ----------------
template<int OUT_BF16>
__global__ __launch_bounds__(256) void gemm_bt(
    const __hip_bfloat16* __restrict__ A,
    const __hip_bfloat16* __restrict__ Bw,
    void* __restrict__ Cout, int M, int N, int K) {
    __shared__ __hip_bfloat16 As[128][72];
    __shared__ __hip_bfloat16 Bs[128][72];
    const int t = threadIdx.x;
    const int lane = t & 63, w = t >> 6;
    const int wr = w >> 1, wc = w & 1;
    const int l15 = lane & 15, lg = lane >> 4;
    const int m0 = blockIdx.y * 128, n0 = blockIdx.x * 128;
    const int srow = t >> 2, scol = (t & 3) * 16;

    f32x4 acc[4][4];
    f32x4 zero4 = {0.f, 0.f, 0.f, 0.f};
#pragma unroll
    for (int m = 0; m < 4; m++)
#pragma unroll
        for (int n = 0; n < 4; n++) acc[m][n] = zero4;

    for (int k0 = 0; k0 < K; k0 += 64) {
        __syncthreads();
#pragma unroll
        for (int i = 0; i < 2; i++) {
            int r = srow + i * 64;
            const uint4* ga = reinterpret_cast<const uint4*>(&A[(size_t)(m0 + r) * K + k0 + scol]);
            uint4 a0 = ga[0], a1 = ga[1];
            const uint4* gb = reinterpret_cast<const uint4*>(&Bw[(size_t)(n0 + r) * K + k0 + scol]);
            uint4 b0 = gb[0], b1 = gb[1];
            *reinterpret_cast<uint4*>(&As[r][scol]) = a0;
            *reinterpret_cast<uint4*>(&As[r][scol + 8]) = a1;
            *reinterpret_cast<uint4*>(&Bs[r][scol]) = b0;
            *reinterpret_cast<uint4*>(&Bs[r][scol + 8]) = b1;
        }
        __syncthreads();
#pragma unroll
        for (int kk = 0; kk < 2; kk++) {
            bf16x8 a[4], b[4];
            const int co = kk * 32 + lg * 8;
#pragma unroll
            for (int m = 0; m < 4; m++)
                a[m] = *reinterpret_cast<const bf16x8*>(&As[wr * 64 + m * 16 + l15][co]);
#pragma unroll
            for (int n = 0; n < 4; n++)
                b[n] = *reinterpret_cast<const bf16x8*>(&Bs[wc * 64 + n * 16 + l15][co]);
#pragma unroll
            for (int m = 0; m < 4; m++)
#pragma unroll
                for (int n = 0; n < 4; n++)
                    acc[m][n] = __builtin_amdgcn_mfma_f32_16x16x32_bf16(a[m], b[n], acc[m][n], 0, 0, 0);
        }
    }
#pragma unroll
    for (int m = 0; m < 4; m++)
#pragma unroll
        for (int n = 0; n < 4; n++)
#pragma unroll
            for (int jj = 0; jj < 4; jj++) {
                int row = m0 + wr * 64 + m * 16 + lg * 4 + jj;
                int col = n0 + wc * 64 + n * 16 + l15;
                float v = acc[m][n][jj];
                if (OUT_BF16)
                    ((__hip_bfloat16*)Cout)[(size_t)row * N + col] = __float2bfloat16(v);
                else
                    ((float*)Cout)[(size_t)row * N + col] = v;
            }
}

// ---------------- RoPE for q,k -> (B,H,T,D); q pre-scaled by 0.125*log2(e) ----------------
__global__ void rope_qk(const __hip_bfloat16* __restrict__ qkv,
                        const float* __restrict__ freqs,
                        __hip_bfloat16* __restrict__ q_s,
                        __hip_bfloat16* __restrict__ k_s) {
    int idx = blockIdx.x * 256 + threadIdx.x;   // BT*H*32 threads
    int i = idx & 31;
    int h = (idx >> 5) & 15;
    int bt = idx >> 9;
    int b = bt >> 11;           // T=2048
    int tp = bt & 2047;
    float th = (float)tp * freqs[i];
    float sn = sinf(th), cs = cosf(th);
    size_t qoff = (size_t)bt * C3 + h * 64;
    float q1 = __bfloat162float(qkv[qoff + 2 * i]);
    float q2 = __bfloat162float(qkv[qoff + 2 * i + 1]);
    float k1 = __bfloat162float(qkv[qoff + C_DIM + 2 * i]);
    float k2 = __bfloat162float(qkv[qoff + C_DIM + 2 * i + 1]);
    size_t obase = ((size_t)(b * H_HEADS + h) * T_SEQ + tp) * D_HEAD;
    const float sc = 0.125f * 1.44269504f;      // 1/sqrt(D) * log2(e)
    q_s[obase + i]      = __float2bfloat16((q1 * cs - q2 * sn) * sc);
    q_s[obase + 32 + i] = __float2bfloat16((q1 * sn + q2 * cs) * sc);
    k_s[obase + i]      = __float2bfloat16(k1 * cs - k2 * sn);
    k_s[obase + 32 + i] = __float2bfloat16(k1 * sn + k2 * cs);
}

// ---------------- V transpose: qkv v-part -> v_t (B,H,D,T) ----------------
__global__ __launch_bounds__(256) void transpose_v(const __hip_bfloat16* __restrict__ qkv,
                                                   __hip_bfloat16* __restrict__ v_t) {
    __shared__ __hip_bfloat16 tile[64][72];
    const int bh = blockIdx.y, tt = blockIdx.x;
    const int b = bh >> 4, h = bh & 15;
    const int t = threadIdx.x;
    const int r = t >> 2, c0 = (t & 3) * 16;
    const __hip_bfloat16* src = qkv + (size_t)(b * T_SEQ + tt * 64 + r) * C3 + 2 * C_DIM + h * 64 + c0;
    uint4 v0 = reinterpret_cast<const uint4*>(src)[0];
    uint4 v1 = reinterpret_cast<const uint4*>(src)[1];
    *reinterpret_cast<uint4*>(&tile[r][c0]) = v0;
    *reinterpret_cast<uint4*>(&tile[r][c0 + 8]) = v1;
    __syncthreads();
    const int d = t >> 2;
    ushort out[16];
#pragma unroll
    for (int i = 0; i < 16; i++) {
        __hip_bfloat16 x = tile[c0 + i][d];
        __builtin_memcpy(&out[i], &x, 2);
    }
    __hip_bfloat16* dst = v_t + (size_t)bh * D_HEAD * T_SEQ + (size_t)d * T_SEQ + tt * 64 + c0;
    reinterpret_cast<uint4*>(dst)[0] = *reinterpret_cast<uint4*>(&out[0]);
    reinterpret_cast<uint4*>(dst)[1] = *reinterpret_cast<uint4*>(&out[8]);
}

// ---------------- flash attention: zero-LDS, swapped-operand, in-register P ----------------
// Block = (head bh, 64-row q tile). 4 waves x 16 q rows. No LDS, no barriers.
// S^T = mfma(K_frag, Q_frag): lane holds P[q = lane&15][k-slice], softmax per-lane.
// K rows permuted across tiles so P stays in-register for PV.
// o^T = mfma(V^T_frag, P_frag): output col = q matches softmax lane.
__global__ __launch_bounds__(256) void attn_kernel(
    const __hip_bfloat16* __restrict__ q_s,
    const __hip_bfloat16* __restrict__ k_s,
    const __hip_bfloat16* __restrict__ v_t,
    __hip_bfloat16* __restrict__ y) {
    // XCD-chunked swizzle: 1024 blocks, 128 consecutive per XCD (4 heads/XCD)
    int flat = blockIdx.x + 32 * blockIdx.y;
    int nf = (flat & 7) * 128 + (flat >> 3);
    const int bh = nf >> 5, qt = nf & 31;
    const int t = threadIdx.x, lane = t & 63, w = t >> 6;
    const int l15 = lane & 15, lg = lane >> 4;
    const size_t hbase = (size_t)bh * T_SEQ * D_HEAD;

    const int qrow = qt * 64 + w * 16 + l15;
    bf16x8 aq[2];
#pragma unroll
    for (int dd = 0; dd < 2; dd++)
        aq[dd] = *reinterpret_cast<const bf16x8*>(&q_s[hbase + (size_t)qrow * 64 + dd * 32 + lg * 8]);

    f32x4 zero4 = {0.f, 0.f, 0.f, 0.f};
    f32x4 o[4];
#pragma unroll
    for (int dc = 0; dc < 4; dc++) o[dc] = zero4;
    float mrow = -INFINITY, lrow = 0.f;

    // K-row permutation: tile c, frag row r -> K row (c>>1)*32 + (r>>2)*8 + (c&1)*4 + (r&3)
    const int krperm = (l15 >> 2) * 8 + (l15 & 3);
    const __hip_bfloat16* kptr = k_s + hbase + (size_t)krperm * 64 + lg * 8;
    const __hip_bfloat16* vptr = v_t + hbase + (size_t)l15 * T_SEQ + lg * 8;

    for (int kt = 0; kt <= qt; kt++) {
        // ---- S^T = K * Q^T (log2 domain, q pre-scaled) ----
        f32x4 st[4];
#pragma unroll
        for (int c = 0; c < 4; c++) {
            st[c] = zero4;
            const __hip_bfloat16* kc = kptr + (size_t)(kt * 64 + (c >> 1) * 32 + (c & 1) * 4) * 64;
#pragma unroll
            for (int dd = 0; dd < 2; dd++) {
                bf16x8 bk = *reinterpret_cast<const bf16x8*>(kc + dd * 32);
                st[c] = __builtin_amdgcn_mfma_f32_16x16x32_bf16(bk, aq[dd], st[c], 0, 0, 0);
            }
        }
        // ---- issue V loads early (hide L2 latency under softmax) ----
        bf16x8 av[4][2];
#pragma unroll
        for (int dc = 0; dc < 4; dc++)
#pragma unroll
            for (int dd = 0; dd < 2; dd++)
                av[dc][dd] = *reinterpret_cast<const bf16x8*>(
                    vptr + (size_t)dc * 16 * T_SEQ + kt * 64 + dd * 32);
        // ---- causal mask (diagonal tile only) ----
        if (kt == qt) {
#pragma unroll
            for (int c = 0; c < 4; c++)
#pragma unroll
                for (int jj = 0; jj < 4; jj++) {
                    int kabs = kt * 64 + (c >> 1) * 32 + lg * 8 + (c & 1) * 4 + jj;
                    if (kabs > qrow) st[c][jj] = -INFINITY;
                }
        }
        // ---- online softmax: lane owns one q row ----
        float mx = st[0][0];
#pragma unroll
        for (int c = 0; c < 4; c++)
#pragma unroll
            for (int jj = 0; jj < 4; jj++) mx = fmaxf(mx, st[c][jj]);
        mx = fmaxf(mx, __shfl_xor(mx, 16));
        mx = fmaxf(mx, __shfl_xor(mx, 32));
        float mnew = fmaxf(mrow, mx);
        float scl = exp2f(mrow - mnew);
        mrow = mnew;
        float rs = 0.f;
#pragma unroll
        for (int c = 0; c < 4; c++)
#pragma unroll
            for (int jj = 0; jj < 4; jj++) {
                float p = exp2f(st[c][jj] - mnew);
                st[c][jj] = p;
                rs += p;
            }
        rs += __shfl_xor(rs, 16);
        rs += __shfl_xor(rs, 32);
        lrow = lrow * scl + rs;
        // ---- pack P (in-register, zero shuffles thanks to K-row permutation) ----
        union { bf16x8 v; unsigned int u[4]; } pf0, pf1;
        pf0.u[0] = pkbf(st[0][0], st[0][1]);
        pf0.u[1] = pkbf(st[0][2], st[0][3]);
        pf0.u[2] = pkbf(st[1][0], st[1][1]);
        pf0.u[3] = pkbf(st[1][2], st[1][3]);
        pf1.u[0] = pkbf(st[2][0], st[2][1]);
        pf1.u[1] = pkbf(st[2][2], st[2][3]);
        pf1.u[2] = pkbf(st[3][0], st[3][1]);
        pf1.u[3] = pkbf(st[3][2], st[3][3]);
        // ---- rescale O, then O^T += V^T P ----
#pragma unroll
        for (int dc = 0; dc < 4; dc++)
#pragma unroll
            for (int jj = 0; jj < 4; jj++) o[dc][jj] *= scl;
#pragma unroll
        for (int dc = 0; dc < 4; dc++) {
            o[dc] = __builtin_amdgcn_mfma_f32_16x16x32_bf16(av[dc][0], pf0.v, o[dc], 0, 0, 0);
            o[dc] = __builtin_amdgcn_mfma_f32_16x16x32_bf16(av[dc][1], pf1.v, o[dc], 0, 0, 0);
        }
    }
    // ---- write y in (B,T,C): lane holds o^T[d = dc*16+lg*4+jj][q = l15] ----
    float inv = 1.f / lrow;
    const int b = bh >> 4, h = bh & 15;
#pragma unroll
    for (int dc = 0; dc < 4; dc++) {
        ushort4 ov;
        ov.x = bf_bits(o[dc][0] * inv);
        ov.y = bf_bits(o[dc][1] * inv);
        ov.z = bf_bits(o[dc][2] * inv);
        ov.w = bf_bits(o[dc][3] * inv);
        *reinterpret_cast<ushort4*>(
            &y[(size_t)(b * T_SEQ + qrow) * C_DIM + h * 64 + dc * 16 + lg * 4]) = ov;
    }
}

// ---------------- LayerNorm over C=1024, one block per row ----------------
__global__ __launch_bounds__(256) void ln_kernel(const float* __restrict__ y2,
                                                 const float* __restrict__ wgt,
                                                 const float* __restrict__ bias,
                                                 float* __restrict__ out) {
    const int row = blockIdx.x;
    const int t = threadIdx.x;
    float4 v = reinterpret_cast<const float4*>(y2 + (size_t)row * C_DIM)[t];
    float s = v.x + v.y + v.z + v.w;
    float s2 = v.x * v.x + v.y * v.y + v.z * v.z + v.w * v.w;
#pragma unroll
    for (int d = 1; d < 64; d <<= 1) {
        s += __shfl_xor(s, d);
        s2 += __shfl_xor(s2, d);
    }
    __shared__ float ps[4], ps2[4];
    const int lane = t & 63, w = t >> 6;
    if (lane == 0) { ps[w] = s; ps2[w] = s2; }
    __syncthreads();
    s = ps[0] + ps[1] + ps[2] + ps[3];
    s2 = ps2[0] + ps2[1] + ps2[2] + ps2[3];
    float mean = s * (1.f / C_DIM);
    float var = s2 * (1.f / C_DIM) - mean * mean;
    float inv = rsqrtf(var + 1e-5f);
    float4 wv = reinterpret_cast<const float4*>(wgt)[t];
    float4 bv = reinterpret_cast<const float4*>(bias)[t];
    float4 ov;
    ov.x = (v.x - mean) * inv * wv.x + bv.x;
    ov.y = (v.y - mean) * inv * wv.y + bv.y;
    ov.z = (v.z - mean) * inv * wv.z + bv.z;
    ov.w = (v.w - mean) * inv * wv.w + bv.w;
    reinterpret_cast<float4*>(out + (size_t)row * C_DIM)[t] = ov;
}

extern "C" void kernel_launch(void* const* d_in, const int* in_sizes, int n_in,
                              void* d_out, int out_size, void* d_ws, size_t ws_size,
                              hipStream_t stream) {
    const float* x      = (const float*)d_in[0];
    const float* freqs  = (const float*)d_in[1];
    const float* W_attn = (const float*)d_in[2];
    const float* W_proj = (const float*)d_in[3];
    const float* lnw    = (const float*)d_in[4];
    const float* lnb    = (const float*)d_in[5];
    float* out = (float*)d_out;
    char* ws = (char*)d_ws;

    __hip_bfloat16* xb   = (__hip_bfloat16*)(ws);                 // 8.4 MB
    __hip_bfloat16* Wab  = (__hip_bfloat16*)(ws + 8388608);       // 6.3 MB
    __hip_bfloat16* Wpb  = (__hip_bfloat16*)(ws + 14680064);      // 2.1 MB
    __hip_bfloat16* qkvb = (__hip_bfloat16*)(ws + 16777216);      // 25.2 MB
    __hip_bfloat16* q_s  = (__hip_bfloat16*)(ws + 41943040);      // 8.4 MB
    __hip_bfloat16* k_s  = (__hip_bfloat16*)(ws + 50331648);      // 8.4 MB
    __hip_bfloat16* v_t  = (__hip_bfloat16*)(ws + 58720256);      // 8.4 MB (B,H,D,T)
    __hip_bfloat16* y_at = (__hip_bfloat16*)(ws + 67108864);      // 8.4 MB
    float*          y2   = (float*)(ws + 75497472);               // 16.8 MB

    // casts
    cast_f32_bf16<<<(BT * C_DIM / 4) / 256, 256, 0, stream>>>(x, xb, BT * C_DIM / 4);
    cast_f32_bf16<<<(C3 * C_DIM / 4) / 256, 256, 0, stream>>>(W_attn, Wab, C3 * C_DIM / 4);
    cast_f32_bf16<<<(C_DIM * C_DIM / 4) / 256, 256, 0, stream>>>(W_proj, Wpb, C_DIM * C_DIM / 4);

    // qkv = x @ W_attn^T
    gemm_bt<1><<<dim3(C3 / 128, BT / 128), 256, 0, stream>>>(xb, Wab, qkvb, BT, C3, C_DIM);

    // rope q,k + transpose v
    rope_qk<<<(BT * H_HEADS * 32) / 256, 256, 0, stream>>>(qkvb, freqs, q_s, k_s);
    transpose_v<<<dim3(T_SEQ / 64, BH), 256, 0, stream>>>(qkvb, v_t);

    // attention
    attn_kernel<<<dim3(T_SEQ / 64, BH), 256, 0, stream>>>(q_s, k_s, v_t, y_at);

    // proj
    gemm_bt<0><<<dim3(C_DIM / 128, BT / 128), 256, 0, stream>>>(y_at, Wpb, y2, BT, C_DIM, C_DIM);

    // layernorm
    ln_kernel<<<BT, 256, 0, stream>>>(y2, lnw, lnb, out);
}

// Round 3
// 179.872 us; speedup vs baseline: 1.7534x; 1.7534x over previous
//
#include <hip/hip_runtime.h>
#include <hip/hip_bf16.h>
#include <math.h>

typedef short bf16x8 __attribute__((ext_vector_type(8)));
typedef float f32x4 __attribute__((ext_vector_type(4)));

#define T_SEQ 2048
#define C_DIM 1024
#define H_HEADS 16
#define D_HEAD 64
#define BT 4096          // B*T
#define C3 3072
#define BH 32            // B*H

static __device__ inline unsigned short bf_bits(float f) {
    __hip_bfloat16 h = __float2bfloat16(f);
    unsigned short u;
    __builtin_memcpy(&u, &h, 2);
    return u;
}

static __device__ inline unsigned int pkbf(float a, float b) {
    return (unsigned int)bf_bits(a) | ((unsigned int)bf_bits(b) << 16);
}

__device__ __forceinline__ void gload16(const void* g, void* l) {
    __builtin_amdgcn_global_load_lds(
        (const __attribute__((address_space(1))) void*)g,
        (__attribute__((address_space(3))) void*)l, 16, 0, 0);
}

// LDS XOR swizzle (element units, 8-elem granule): spreads rows across bank quads
__device__ __forceinline__ int swz(int r) {
    return ((((r & 3) ^ ((r >> 3) & 3)) | (((r >> 3) & 1) << 2)) << 3);
}

// ---------------- cast f32 -> bf16, 4 elems/thread ----------------
__global__ void cast_f32_bf16(const float* __restrict__ in,
                              __hip_bfloat16* __restrict__ out, int n4) {
    int i = blockIdx.x * blockDim.x + threadIdx.x;
    if (i >= n4) return;
    float4 v = reinterpret_cast<const float4*>(in)[i];
    ushort4 o;
    o.x = bf_bits(v.x); o.y = bf_bits(v.y); o.z = bf_bits(v.z); o.w = bf_bits(v.w);
    reinterpret_cast<ushort4*>(out)[i] = o;
}

// ---------------- GEMM: Cout = A(M,K) * Bw(N,K)^T, bf16 MFMA, global_load_lds ----------------
template<int OUT_BF16>
__global__ __launch_bounds__(256) void gemm_bt(
    const __hip_bfloat16* __restrict__ A,
    const __hip_bfloat16* __restrict__ Bw,
    void* __restrict__ Cout, int M, int N, int K) {
    __shared__ __hip_bfloat16 As[128][64];
    __shared__ __hip_bfloat16 Bs[128][64];
    const int t = threadIdx.x;
    const int lane = t & 63, w = t >> 6;
    const int wr = w >> 1, wc = w & 1;
    const int l15 = lane & 15, lg = lane >> 4;
    const int m0 = blockIdx.y * 128, n0 = blockIdx.x * 128;

    f32x4 acc[4][4];
    f32x4 zero4 = {0.f, 0.f, 0.f, 0.f};
#pragma unroll
    for (int m = 0; m < 4; m++)
#pragma unroll
        for (int n = 0; n < 4; n++) acc[m][n] = zero4;

    const int srow_in_call = lane >> 3;        // 0..7
    const int scol = (lane & 7) * 8;           // elems

    for (int k0 = 0; k0 < K; k0 += 64) {
        __syncthreads();
#pragma unroll
        for (int i = 0; i < 4; i++) {
            int rbase = w * 32 + i * 8;
            int row = rbase + srow_in_call;
            gload16(&A[(size_t)(m0 + row) * K + k0 + scol], &As[rbase][0]);
            gload16(&Bw[(size_t)(n0 + row) * K + k0 + scol], &Bs[rbase][0]);
        }
        __syncthreads();
#pragma unroll
        for (int kk = 0; kk < 2; kk++) {
            bf16x8 a[4], b[4];
            const int co = kk * 32 + lg * 8;
#pragma unroll
            for (int m = 0; m < 4; m++)
                a[m] = *reinterpret_cast<const bf16x8*>(&As[wr * 64 + m * 16 + l15][co]);
#pragma unroll
            for (int n = 0; n < 4; n++)
                b[n] = *reinterpret_cast<const bf16x8*>(&Bs[wc * 64 + n * 16 + l15][co]);
#pragma unroll
            for (int m = 0; m < 4; m++)
#pragma unroll
                for (int n = 0; n < 4; n++)
                    acc[m][n] = __builtin_amdgcn_mfma_f32_16x16x32_bf16(a[m], b[n], acc[m][n], 0, 0, 0);
        }
    }
#pragma unroll
    for (int m = 0; m < 4; m++)
#pragma unroll
        for (int n = 0; n < 4; n++)
#pragma unroll
            for (int jj = 0; jj < 4; jj++) {
                int row = m0 + wr * 64 + m * 16 + lg * 4 + jj;
                int col = n0 + wc * 64 + n * 16 + l15;
                float v = acc[m][n][jj];
                if (OUT_BF16)
                    ((__hip_bfloat16*)Cout)[(size_t)row * N + col] = __float2bfloat16(v);
                else
                    ((float*)Cout)[(size_t)row * N + col] = v;
            }
}

// ---------------- RoPE for q,k -> (B,H,T,D); q pre-scaled by 0.125*log2(e) ----------------
__global__ void rope_qk(const __hip_bfloat16* __restrict__ qkv,
                        const float* __restrict__ freqs,
                        __hip_bfloat16* __restrict__ q_s,
                        __hip_bfloat16* __restrict__ k_s) {
    int idx = blockIdx.x * 256 + threadIdx.x;   // BT*H*32 threads
    int i = idx & 31;
    int h = (idx >> 5) & 15;
    int bt = idx >> 9;
    int b = bt >> 11;           // T=2048
    int tp = bt & 2047;
    float th = (float)tp * freqs[i];
    float sn = sinf(th), cs = cosf(th);
    size_t qoff = (size_t)bt * C3 + h * 64;
    float q1 = __bfloat162float(qkv[qoff + 2 * i]);
    float q2 = __bfloat162float(qkv[qoff + 2 * i + 1]);
    float k1 = __bfloat162float(qkv[qoff + C_DIM + 2 * i]);
    float k2 = __bfloat162float(qkv[qoff + C_DIM + 2 * i + 1]);
    size_t obase = ((size_t)(b * H_HEADS + h) * T_SEQ + tp) * D_HEAD;
    const float sc = 0.125f * 1.44269504f;      // 1/sqrt(D) * log2(e)
    q_s[obase + i]      = __float2bfloat16((q1 * cs - q2 * sn) * sc);
    q_s[obase + 32 + i] = __float2bfloat16((q1 * sn + q2 * cs) * sc);
    k_s[obase + i]      = __float2bfloat16(k1 * cs - k2 * sn);
    k_s[obase + 32 + i] = __float2bfloat16(k1 * sn + k2 * cs);
}

// ---------------- V transpose: qkv v-part -> v_t (B,H,D,T) ----------------
__global__ __launch_bounds__(256) void transpose_v(const __hip_bfloat16* __restrict__ qkv,
                                                   __hip_bfloat16* __restrict__ v_t) {
    __shared__ __hip_bfloat16 tile[64][72];
    const int bh = blockIdx.y, tt = blockIdx.x;
    const int b = bh >> 4, h = bh & 15;
    const int t = threadIdx.x;
    const int r = t >> 2, c0 = (t & 3) * 16;
    const __hip_bfloat16* src = qkv + (size_t)(b * T_SEQ + tt * 64 + r) * C3 + 2 * C_DIM + h * 64 + c0;
    uint4 v0 = reinterpret_cast<const uint4*>(src)[0];
    uint4 v1 = reinterpret_cast<const uint4*>(src)[1];
    *reinterpret_cast<uint4*>(&tile[r][c0]) = v0;
    *reinterpret_cast<uint4*>(&tile[r][c0 + 8]) = v1;
    __syncthreads();
    const int d = t >> 2;
    ushort out[16];
#pragma unroll
    for (int i = 0; i < 16; i++) {
        __hip_bfloat16 x = tile[c0 + i][d];
        __builtin_memcpy(&out[i], &x, 2);
    }
    __hip_bfloat16* dst = v_t + (size_t)bh * D_HEAD * T_SEQ + (size_t)d * T_SEQ + tt * 64 + c0;
    reinterpret_cast<uint4*>(dst)[0] = *reinterpret_cast<uint4*>(&out[0]);
    reinterpret_cast<uint4*>(dst)[1] = *reinterpret_cast<uint4*>(&out[8]);
}

// ---------------- flash attention ----------------
// Block = (head bh, 128-row q tile). 4 waves; wave w owns rows {w*16..+15, 64+w*16..+15}
// (2 fragments, interleaved for causal load balance). K and V^T tiles (64x64) staged in
// LDS, XOR-swizzled, double-buffered; T14 issue-early/write-late. Swapped QK^T: lane
// owns q=l15 row, softmax per-lane in-register, P stays in registers for PV.
__global__ __launch_bounds__(256) void attn_kernel(
    const __hip_bfloat16* __restrict__ q_s,
    const __hip_bfloat16* __restrict__ k_s,
    const __hip_bfloat16* __restrict__ v_t,
    __hip_bfloat16* __restrict__ y) {
    __shared__ ushort Kbuf[2][64 * 64];
    __shared__ ushort Vbuf[2][64 * 64];

    const int bid = blockIdx.x;                 // 512 blocks
    const int qt = 15 - (bid >> 5);             // LPT: longest first
    const int bh = bid & 31;                    // bh%8 == bid%8 -> head-per-XCD locality
    const int t = threadIdx.x, lane = t & 63, w = t >> 6;
    const int l15 = lane & 15, lg = lane >> 4;
    const size_t hbase = (size_t)bh * T_SEQ * D_HEAD;
    const int qbase = qt * 128;

    const int fb0 = qbase + w * 16;             // frag 0 rows
    const int fb1 = qbase + 64 + w * 16;        // frag 1 rows
    const int qr0 = fb0 + l15, qr1 = fb1 + l15;

    // Q fragments
    bf16x8 aq0[2], aq1[2];
#pragma unroll
    for (int dd = 0; dd < 2; dd++) {
        aq0[dd] = *reinterpret_cast<const bf16x8*>(&q_s[hbase + (size_t)qr0 * 64 + dd * 32 + lg * 8]);
        aq1[dd] = *reinterpret_cast<const bf16x8*>(&q_s[hbase + (size_t)qr1 * 64 + dd * 32 + lg * 8]);
    }

    f32x4 zero4 = {0.f, 0.f, 0.f, 0.f};
    f32x4 o0[4], o1[4];
#pragma unroll
    for (int dc = 0; dc < 4; dc++) { o0[dc] = zero4; o1[dc] = zero4; }
    float m0_ = -INFINITY, l0_ = 0.f, m1_ = -INFINITY, l1_ = 0.f;

    // LDS read offsets (element units), hoisted
    int koff[4][2], voff[4][2];
#pragma unroll
    for (int c = 0; c < 4; c++) {
        int kro = ((c >> 1) << 5) + ((c & 1) << 2) + ((l15 >> 2) << 3) + (l15 & 3);
        int sz = swz(kro);
#pragma unroll
        for (int dd = 0; dd < 2; dd++)
            koff[c][dd] = kro * 64 + ((dd * 32 + lg * 8) ^ sz);
    }
#pragma unroll
    for (int dc = 0; dc < 4; dc++) {
        int vro = dc * 16 + l15;
        int sz = swz(vro);
#pragma unroll
        for (int dd = 0; dd < 2; dd++)
            voff[dc][dd] = vro * 64 + ((dd * 32 + lg * 8) ^ sz);
    }

    // staging geometry
    const int ssr = t >> 2;                 // tile row 0..63
    const int sse = (t & 3) * 16;           // elem col {0,16,32,48}
    const int sw = swz(ssr);
    const int w0 = ssr * 64 + (sse ^ sw);
    const int w1 = ssr * 64 + ((sse + 8) ^ sw);

    const int last = 2 * qt + 1;
    int cur = 0;
    int kt64 = 0;

    // prologue: stage tile 0
    {
        const __hip_bfloat16* kg = k_s + hbase + (size_t)ssr * 64 + sse;
        uint4 a0 = reinterpret_cast<const uint4*>(kg)[0];
        uint4 a1 = reinterpret_cast<const uint4*>(kg)[1];
        const __hip_bfloat16* vg = v_t + hbase + (size_t)ssr * T_SEQ + sse;
        uint4 b0 = reinterpret_cast<const uint4*>(vg)[0];
        uint4 b1 = reinterpret_cast<const uint4*>(vg)[1];
        *reinterpret_cast<uint4*>(&Kbuf[0][w0]) = a0;
        *reinterpret_cast<uint4*>(&Kbuf[0][w1]) = a1;
        *reinterpret_cast<uint4*>(&Vbuf[0][w0]) = b0;
        *reinterpret_cast<uint4*>(&Vbuf[0][w1]) = b1;
    }
    __syncthreads();

    auto frag_step = [&](const bf16x8 (&aqf)[2], const bf16x8 (&kf)[4][2],
                         const bf16x8 (&av)[4][2], f32x4 (&o)[4],
                         float& mr, float& lr, int qr, bool domask) {
        f32x4 st[4];
#pragma unroll
        for (int c = 0; c < 4; c++) {
            st[c] = zero4;
#pragma unroll
            for (int dd = 0; dd < 2; dd++)
                st[c] = __builtin_amdgcn_mfma_f32_16x16x32_bf16(kf[c][dd], aqf[dd], st[c], 0, 0, 0);
        }
        if (domask) {
#pragma unroll
            for (int c = 0; c < 4; c++) {
                int kb = kt64 + ((c >> 1) << 5) + ((c & 1) << 2) + lg * 8;
#pragma unroll
                for (int jj = 0; jj < 4; jj++)
                    if (kb + jj > qr) st[c][jj] = -INFINITY;
            }
        }
        float mx = fmaxf(fmaxf(st[0][0], st[0][1]), fmaxf(st[0][2], st[0][3]));
#pragma unroll
        for (int c = 1; c < 4; c++)
            mx = fmaxf(mx, fmaxf(fmaxf(st[c][0], st[c][1]), fmaxf(st[c][2], st[c][3])));
        mx = fmaxf(mx, __shfl_xor(mx, 16));
        mx = fmaxf(mx, __shfl_xor(mx, 32));
        float mnew = fmaxf(mr, mx);
        float scl = exp2f(mr - mnew);
        mr = mnew;
        float rs = 0.f;
#pragma unroll
        for (int c = 0; c < 4; c++)
#pragma unroll
            for (int jj = 0; jj < 4; jj++) {
                float p = exp2f(st[c][jj] - mnew);
                st[c][jj] = p;
                rs += p;
            }
        rs += __shfl_xor(rs, 16);
        rs += __shfl_xor(rs, 32);
        lr = lr * scl + rs;
        union { bf16x8 v; unsigned int u[4]; } pf0, pf1;
        pf0.u[0] = pkbf(st[0][0], st[0][1]);
        pf0.u[1] = pkbf(st[0][2], st[0][3]);
        pf0.u[2] = pkbf(st[1][0], st[1][1]);
        pf0.u[3] = pkbf(st[1][2], st[1][3]);
        pf1.u[0] = pkbf(st[2][0], st[2][1]);
        pf1.u[1] = pkbf(st[2][2], st[2][3]);
        pf1.u[2] = pkbf(st[3][0], st[3][1]);
        pf1.u[3] = pkbf(st[3][2], st[3][3]);
#pragma unroll
        for (int dc = 0; dc < 4; dc++)
#pragma unroll
            for (int jj = 0; jj < 4; jj++) o[dc][jj] *= scl;
#pragma unroll
        for (int dc = 0; dc < 4; dc++) {
            o[dc] = __builtin_amdgcn_mfma_f32_16x16x32_bf16(av[dc][0], pf0.v, o[dc], 0, 0, 0);
            o[dc] = __builtin_amdgcn_mfma_f32_16x16x32_bf16(av[dc][1], pf1.v, o[dc], 0, 0, 0);
        }
    };

    for (int kt = 0; kt <= last; kt++) {
        kt64 = kt << 6;
        const bool hn = kt < last;
        uint4 nk0, nk1, nv0, nv1;
        if (hn) {   // issue next-tile loads early (latency hides under compute)
            const __hip_bfloat16* kg = k_s + hbase + (size_t)(kt64 + 64 + ssr) * 64 + sse;
            nk0 = reinterpret_cast<const uint4*>(kg)[0];
            nk1 = reinterpret_cast<const uint4*>(kg)[1];
            const __hip_bfloat16* vg = v_t + hbase + (size_t)ssr * T_SEQ + kt64 + 64 + sse;
            nv0 = reinterpret_cast<const uint4*>(vg)[0];
            nv1 = reinterpret_cast<const uint4*>(vg)[1];
        }
        if (kt64 <= fb1 + 15) {     // frag1 active (implies maybe frag0)
            const ushort* Kc = Kbuf[cur];
            const ushort* Vc = Vbuf[cur];
            bf16x8 kf[4][2], av[4][2];
#pragma unroll
            for (int c = 0; c < 4; c++)
#pragma unroll
                for (int dd = 0; dd < 2; dd++)
                    kf[c][dd] = *reinterpret_cast<const bf16x8*>(&Kc[koff[c][dd]]);
#pragma unroll
            for (int dc = 0; dc < 4; dc++)
#pragma unroll
                for (int dd = 0; dd < 2; dd++)
                    av[dc][dd] = *reinterpret_cast<const bf16x8*>(&Vc[voff[dc][dd]]);
            frag_step(aq1, kf, av, o1, m1_, l1_, qr1, kt == (fb1 >> 6));
            if (kt64 <= fb0 + 15)
                frag_step(aq0, kf, av, o0, m0_, l0_, qr0, kt == (fb0 >> 6));
        }
        if (hn) {   // write-late into the other buffer
            ushort* Kn = Kbuf[cur ^ 1];
            ushort* Vn = Vbuf[cur ^ 1];
            *reinterpret_cast<uint4*>(&Kn[w0]) = nk0;
            *reinterpret_cast<uint4*>(&Kn[w1]) = nk1;
            *reinterpret_cast<uint4*>(&Vn[w0]) = nv0;
            *reinterpret_cast<uint4*>(&Vn[w1]) = nv1;
        }
        __syncthreads();
        cur ^= 1;
    }

    // epilogue: lane holds o^T[d = dc*16 + lg*4 + jj][q = l15]
    const int b = bh >> 4, h = bh & 15;
    float inv0 = 1.f / l0_, inv1 = 1.f / l1_;
#pragma unroll
    for (int dc = 0; dc < 4; dc++) {
        ushort4 ov;
        ov.x = bf_bits(o0[dc][0] * inv0);
        ov.y = bf_bits(o0[dc][1] * inv0);
        ov.z = bf_bits(o0[dc][2] * inv0);
        ov.w = bf_bits(o0[dc][3] * inv0);
        *reinterpret_cast<ushort4*>(
            &y[(size_t)(b * T_SEQ + qr0) * C_DIM + h * 64 + dc * 16 + lg * 4]) = ov;
        ushort4 o2;
        o2.x = bf_bits(o1[dc][0] * inv1);
        o2.y = bf_bits(o1[dc][1] * inv1);
        o2.z = bf_bits(o1[dc][2] * inv1);
        o2.w = bf_bits(o1[dc][3] * inv1);
        *reinterpret_cast<ushort4*>(
            &y[(size_t)(b * T_SEQ + qr1) * C_DIM + h * 64 + dc * 16 + lg * 4]) = o2;
    }
}

// ---------------- LayerNorm over C=1024, one block per row ----------------
__global__ __launch_bounds__(256) void ln_kernel(const float* __restrict__ y2,
                                                 const float* __restrict__ wgt,
                                                 const float* __restrict__ bias,
                                                 float* __restrict__ out) {
    const int row = blockIdx.x;
    const int t = threadIdx.x;
    float4 v = reinterpret_cast<const float4*>(y2 + (size_t)row * C_DIM)[t];
    float s = v.x + v.y + v.z + v.w;
    float s2 = v.x * v.x + v.y * v.y + v.z * v.z + v.w * v.w;
#pragma unroll
    for (int d = 1; d < 64; d <<= 1) {
        s += __shfl_xor(s, d);
        s2 += __shfl_xor(s2, d);
    }
    __shared__ float ps[4], ps2[4];
    const int lane = t & 63, w = t >> 6;
    if (lane == 0) { ps[w] = s; ps2[w] = s2; }
    __syncthreads();
    s = ps[0] + ps[1] + ps[2] + ps[3];
    s2 = ps2[0] + ps2[1] + ps2[2] + ps2[3];
    float mean = s * (1.f / C_DIM);
    float var = s2 * (1.f / C_DIM) - mean * mean;
    float inv = rsqrtf(var + 1e-5f);
    float4 wv = reinterpret_cast<const float4*>(wgt)[t];
    float4 bv = reinterpret_cast<const float4*>(bias)[t];
    float4 ov;
    ov.x = (v.x - mean) * inv * wv.x + bv.x;
    ov.y = (v.y - mean) * inv * wv.y + bv.y;
    ov.z = (v.z - mean) * inv * wv.z + bv.z;
    ov.w = (v.w - mean) * inv * wv.w + bv.w;
    reinterpret_cast<float4*>(out + (size_t)row * C_DIM)[t] = ov;
}

extern "C" void kernel_launch(void* const* d_in, const int* in_sizes, int n_in,
                              void* d_out, int out_size, void* d_ws, size_t ws_size,
                              hipStream_t stream) {
    const float* x      = (const float*)d_in[0];
    const float* freqs  = (const float*)d_in[1];
    const float* W_attn = (const float*)d_in[2];
    const float* W_proj = (const float*)d_in[3];
    const float* lnw    = (const float*)d_in[4];
    const float* lnb    = (const float*)d_in[5];
    float* out = (float*)d_out;
    char* ws = (char*)d_ws;

    __hip_bfloat16* xb   = (__hip_bfloat16*)(ws);                 // 8.4 MB
    __hip_bfloat16* Wab  = (__hip_bfloat16*)(ws + 8388608);       // 6.3 MB
    __hip_bfloat16* Wpb  = (__hip_bfloat16*)(ws + 14680064);      // 2.1 MB
    __hip_bfloat16* qkvb = (__hip_bfloat16*)(ws + 16777216);      // 25.2 MB
    __hip_bfloat16* q_s  = (__hip_bfloat16*)(ws + 41943040);      // 8.4 MB
    __hip_bfloat16* k_s  = (__hip_bfloat16*)(ws + 50331648);      // 8.4 MB
    __hip_bfloat16* v_t  = (__hip_bfloat16*)(ws + 58720256);      // 8.4 MB (B,H,D,T)
    __hip_bfloat16* y_at = (__hip_bfloat16*)(ws + 67108864);      // 8.4 MB
    float*          y2   = (float*)(ws + 75497472);               // 16.8 MB

    // casts
    cast_f32_bf16<<<(BT * C_DIM / 4) / 256, 256, 0, stream>>>(x, xb, BT * C_DIM / 4);
    cast_f32_bf16<<<(C3 * C_DIM / 4) / 256, 256, 0, stream>>>(W_attn, Wab, C3 * C_DIM / 4);
    cast_f32_bf16<<<(C_DIM * C_DIM / 4) / 256, 256, 0, stream>>>(W_proj, Wpb, C_DIM * C_DIM / 4);

    // qkv = x @ W_attn^T
    gemm_bt<1><<<dim3(C3 / 128, BT / 128), 256, 0, stream>>>(xb, Wab, qkvb, BT, C3, C_DIM);

    // rope q,k + transpose v
    rope_qk<<<(BT * H_HEADS * 32) / 256, 256, 0, stream>>>(qkvb, freqs, q_s, k_s);
    transpose_v<<<dim3(T_SEQ / 64, BH), 256, 0, stream>>>(qkvb, v_t);

    // attention: 512 blocks (16 q-tiles x 32 heads), LPT order
    attn_kernel<<<512, 256, 0, stream>>>(q_s, k_s, v_t, y_at);

    // proj
    gemm_bt<0><<<dim3(C_DIM / 128, BT / 128), 256, 0, stream>>>(y_at, Wpb, y2, BT, C_DIM, C_DIM);

    // layernorm
    ln_kernel<<<BT, 256, 0, stream>>>(y2, lnw, lnb, out);
}

// Round 4
// 151.525 us; speedup vs baseline: 2.0815x; 1.1871x over previous
//
#include <hip/hip_runtime.h>
#include <hip/hip_bf16.h>
#include <math.h>

typedef short bf16x8 __attribute__((ext_vector_type(8)));
typedef float f32x4 __attribute__((ext_vector_type(4)));

#define T_SEQ 2048
#define C_DIM 1024
#define H_HEADS 16
#define D_HEAD 64
#define BT 4096          // B*T
#define C3 3072
#define BH 32            // B*H

static __device__ inline unsigned short bf_bits(float f) {
    __hip_bfloat16 h = __float2bfloat16(f);
    unsigned short u;
    __builtin_memcpy(&u, &h, 2);
    return u;
}

static __device__ inline unsigned int pkbf(float a, float b) {
    return (unsigned int)bf_bits(a) | ((unsigned int)bf_bits(b) << 16);
}

__device__ __forceinline__ void gload16(const void* g, void* l) {
    __builtin_amdgcn_global_load_lds(
        (const __attribute__((address_space(1))) void*)g,
        (__attribute__((address_space(3))) void*)l, 16, 0, 0);
}

// LDS XOR swizzle (element units, 8-elem granule): spreads rows across bank quads
__device__ __forceinline__ int swz(int r) {
    return ((((r & 3) ^ ((r >> 3) & 3)) | (((r >> 3) & 1) << 2)) << 3);
}

// ---------------- cast f32 -> bf16, 4 elems/thread ----------------
__global__ void cast_f32_bf16(const float* __restrict__ in,
                              __hip_bfloat16* __restrict__ out, int n4) {
    int i = blockIdx.x * blockDim.x + threadIdx.x;
    if (i >= n4) return;
    float4 v = reinterpret_cast<const float4*>(in)[i];
    ushort4 o;
    o.x = bf_bits(v.x); o.y = bf_bits(v.y); o.z = bf_bits(v.z); o.w = bf_bits(v.w);
    reinterpret_cast<ushort4*>(out)[i] = o;
}

// ---------------- GEMM: Cout = A(M,K) * Bw(N,K)^T, bf16 MFMA, global_load_lds ----------------
template<int OUT_BF16>
__global__ __launch_bounds__(256) void gemm_bt(
    const __hip_bfloat16* __restrict__ A,
    const __hip_bfloat16* __restrict__ Bw,
    void* __restrict__ Cout, int M, int N, int K) {
    __shared__ __hip_bfloat16 As[128][64];
    __shared__ __hip_bfloat16 Bs[128][64];
    const int t = threadIdx.x;
    const int lane = t & 63, w = t >> 6;
    const int wr = w >> 1, wc = w & 1;
    const int l15 = lane & 15, lg = lane >> 4;
    const int m0 = blockIdx.y * 128, n0 = blockIdx.x * 128;

    f32x4 acc[4][4];
    f32x4 zero4 = {0.f, 0.f, 0.f, 0.f};
#pragma unroll
    for (int m = 0; m < 4; m++)
#pragma unroll
        for (int n = 0; n < 4; n++) acc[m][n] = zero4;

    const int srow_in_call = lane >> 3;        // 0..7
    const int scol = (lane & 7) * 8;           // elems

    for (int k0 = 0; k0 < K; k0 += 64) {
        __syncthreads();
#pragma unroll
        for (int i = 0; i < 4; i++) {
            int rbase = w * 32 + i * 8;
            int row = rbase + srow_in_call;
            gload16(&A[(size_t)(m0 + row) * K + k0 + scol], &As[rbase][0]);
            gload16(&Bw[(size_t)(n0 + row) * K + k0 + scol], &Bs[rbase][0]);
        }
        __syncthreads();
#pragma unroll
        for (int kk = 0; kk < 2; kk++) {
            bf16x8 a[4], b[4];
            const int co = kk * 32 + lg * 8;
#pragma unroll
            for (int m = 0; m < 4; m++)
                a[m] = *reinterpret_cast<const bf16x8*>(&As[wr * 64 + m * 16 + l15][co]);
#pragma unroll
            for (int n = 0; n < 4; n++)
                b[n] = *reinterpret_cast<const bf16x8*>(&Bs[wc * 64 + n * 16 + l15][co]);
#pragma unroll
            for (int m = 0; m < 4; m++)
#pragma unroll
                for (int n = 0; n < 4; n++)
                    acc[m][n] = __builtin_amdgcn_mfma_f32_16x16x32_bf16(a[m], b[n], acc[m][n], 0, 0, 0);
        }
    }
#pragma unroll
    for (int m = 0; m < 4; m++)
#pragma unroll
        for (int n = 0; n < 4; n++)
#pragma unroll
            for (int jj = 0; jj < 4; jj++) {
                int row = m0 + wr * 64 + m * 16 + lg * 4 + jj;
                int col = n0 + wc * 64 + n * 16 + l15;
                float v = acc[m][n][jj];
                if (OUT_BF16)
                    ((__hip_bfloat16*)Cout)[(size_t)row * N + col] = __float2bfloat16(v);
                else
                    ((float*)Cout)[(size_t)row * N + col] = v;
            }
}

// ---------------- RoPE for q,k -> (B,H,T,D); q pre-scaled by 0.125*log2(e) ----------------
__global__ void rope_qk(const __hip_bfloat16* __restrict__ qkv,
                        const float* __restrict__ freqs,
                        __hip_bfloat16* __restrict__ q_s,
                        __hip_bfloat16* __restrict__ k_s) {
    int idx = blockIdx.x * 256 + threadIdx.x;   // BT*H*32 threads
    int i = idx & 31;
    int h = (idx >> 5) & 15;
    int bt = idx >> 9;
    int b = bt >> 11;           // T=2048
    int tp = bt & 2047;
    float th = (float)tp * freqs[i];
    float sn = sinf(th), cs = cosf(th);
    size_t qoff = (size_t)bt * C3 + h * 64;
    float q1 = __bfloat162float(qkv[qoff + 2 * i]);
    float q2 = __bfloat162float(qkv[qoff + 2 * i + 1]);
    float k1 = __bfloat162float(qkv[qoff + C_DIM + 2 * i]);
    float k2 = __bfloat162float(qkv[qoff + C_DIM + 2 * i + 1]);
    size_t obase = ((size_t)(b * H_HEADS + h) * T_SEQ + tp) * D_HEAD;
    const float sc = 0.125f * 1.44269504f;      // 1/sqrt(D) * log2(e)
    q_s[obase + i]      = __float2bfloat16((q1 * cs - q2 * sn) * sc);
    q_s[obase + 32 + i] = __float2bfloat16((q1 * sn + q2 * cs) * sc);
    k_s[obase + i]      = __float2bfloat16(k1 * cs - k2 * sn);
    k_s[obase + 32 + i] = __float2bfloat16(k1 * sn + k2 * cs);
}

// ---------------- V transpose: qkv v-part -> v_t (B,H,D,T) ----------------
__global__ __launch_bounds__(256) void transpose_v(const __hip_bfloat16* __restrict__ qkv,
                                                   __hip_bfloat16* __restrict__ v_t) {
    __shared__ __hip_bfloat16 tile[64][72];
    const int bh = blockIdx.y, tt = blockIdx.x;
    const int b = bh >> 4, h = bh & 15;
    const int t = threadIdx.x;
    const int r = t >> 2, c0 = (t & 3) * 16;
    const __hip_bfloat16* src = qkv + (size_t)(b * T_SEQ + tt * 64 + r) * C3 + 2 * C_DIM + h * 64 + c0;
    uint4 v0 = reinterpret_cast<const uint4*>(src)[0];
    uint4 v1 = reinterpret_cast<const uint4*>(src)[1];
    *reinterpret_cast<uint4*>(&tile[r][c0]) = v0;
    *reinterpret_cast<uint4*>(&tile[r][c0 + 8]) = v1;
    __syncthreads();
    const int d = t >> 2;
    ushort out[16];
#pragma unroll
    for (int i = 0; i < 16; i++) {
        __hip_bfloat16 x = tile[c0 + i][d];
        __builtin_memcpy(&out[i], &x, 2);
    }
    __hip_bfloat16* dst = v_t + (size_t)bh * D_HEAD * T_SEQ + (size_t)d * T_SEQ + tt * 64 + c0;
    reinterpret_cast<uint4*>(dst)[0] = *reinterpret_cast<uint4*>(&out[0]);
    reinterpret_cast<uint4*>(dst)[1] = *reinterpret_cast<uint4*>(&out[8]);
}

// ---------------- flash attention ----------------
// Block = (head bh, 64-row q tile); 1024 blocks -> 4 blocks/CU co-resident.
// Wave w owns rows qbase + w*16 .. +15 (one fragment). K,V^T staged in LDS
// (XOR-swizzled, double-buffered, issue-early/write-late). Swapped QK^T: lane
// owns q=l15 row; softmax per-lane in-register with tree reductions + defer-max;
// P stays in registers for PV.
__global__ __launch_bounds__(256, 4) void attn_kernel(
    const __hip_bfloat16* __restrict__ q_s,
    const __hip_bfloat16* __restrict__ k_s,
    const __hip_bfloat16* __restrict__ v_t,
    __hip_bfloat16* __restrict__ y) {
    __shared__ ushort Kbuf[2][64 * 64];
    __shared__ ushort Vbuf[2][64 * 64];

    const int bid = blockIdx.x;                 // 1024 blocks
    const int qt = 31 - (bid >> 5);             // LPT: longest first
    const int bh = bid & 31;                    // bh%8 -> head-per-XCD L2 locality
    const int t = threadIdx.x, lane = t & 63, w = t >> 6;
    const int l15 = lane & 15, lg = lane >> 4;
    const size_t hbase = (size_t)bh * T_SEQ * D_HEAD;
    const int qbase = qt * 64;
    const int qr = qbase + w * 16 + l15;

    // Q fragment
    bf16x8 aq[2];
#pragma unroll
    for (int dd = 0; dd < 2; dd++)
        aq[dd] = *reinterpret_cast<const bf16x8*>(&q_s[hbase + (size_t)qr * 64 + dd * 32 + lg * 8]);

    f32x4 zero4 = {0.f, 0.f, 0.f, 0.f};
    f32x4 o[4];
#pragma unroll
    for (int dc = 0; dc < 4; dc++) o[dc] = zero4;
    float mr = -INFINITY, lr = 0.f;

    // LDS read offsets (element units), hoisted
    int koff[4][2], voff[4][2];
#pragma unroll
    for (int c = 0; c < 4; c++) {
        int kro = ((c >> 1) << 5) + ((c & 1) << 2) + ((l15 >> 2) << 3) + (l15 & 3);
        int sz = swz(kro);
#pragma unroll
        for (int dd = 0; dd < 2; dd++)
            koff[c][dd] = kro * 64 + ((dd * 32 + lg * 8) ^ sz);
    }
#pragma unroll
    for (int dc = 0; dc < 4; dc++) {
        int vro = dc * 16 + l15;
        int sz = swz(vro);
#pragma unroll
        for (int dd = 0; dd < 2; dd++)
            voff[dc][dd] = vro * 64 + ((dd * 32 + lg * 8) ^ sz);
    }

    // staging geometry
    const int ssr = t >> 2;                 // tile row 0..63
    const int sse = (t & 3) * 16;           // elem col {0,16,32,48}
    const int sw = swz(ssr);
    const int w0 = ssr * 64 + (sse ^ sw);
    const int w1 = ssr * 64 + ((sse + 8) ^ sw);

    int cur = 0;

    // prologue: stage tile 0
    {
        const __hip_bfloat16* kg = k_s + hbase + (size_t)ssr * 64 + sse;
        uint4 a0 = reinterpret_cast<const uint4*>(kg)[0];
        uint4 a1 = reinterpret_cast<const uint4*>(kg)[1];
        const __hip_bfloat16* vg = v_t + hbase + (size_t)ssr * T_SEQ + sse;
        uint4 b0 = reinterpret_cast<const uint4*>(vg)[0];
        uint4 b1 = reinterpret_cast<const uint4*>(vg)[1];
        *reinterpret_cast<uint4*>(&Kbuf[0][w0]) = a0;
        *reinterpret_cast<uint4*>(&Kbuf[0][w1]) = a1;
        *reinterpret_cast<uint4*>(&Vbuf[0][w0]) = b0;
        *reinterpret_cast<uint4*>(&Vbuf[0][w1]) = b1;
    }
    __syncthreads();

    for (int kt = 0; kt <= qt; kt++) {
        const int kt64 = kt << 6;
        const bool hn = kt < qt;
        uint4 nk0, nk1, nv0, nv1;
        if (hn) {   // issue next-tile loads early (latency hides under compute)
            const __hip_bfloat16* kg = k_s + hbase + (size_t)(kt64 + 64 + ssr) * 64 + sse;
            nk0 = reinterpret_cast<const uint4*>(kg)[0];
            nk1 = reinterpret_cast<const uint4*>(kg)[1];
            const __hip_bfloat16* vg = v_t + hbase + (size_t)ssr * T_SEQ + kt64 + 64 + sse;
            nv0 = reinterpret_cast<const uint4*>(vg)[0];
            nv1 = reinterpret_cast<const uint4*>(vg)[1];
        }
        const ushort* Kc = Kbuf[cur];
        const ushort* Vc = Vbuf[cur];
        bf16x8 kf[4][2], av[4][2];
#pragma unroll
        for (int c = 0; c < 4; c++)
#pragma unroll
            for (int dd = 0; dd < 2; dd++)
                kf[c][dd] = *reinterpret_cast<const bf16x8*>(&Kc[koff[c][dd]]);
#pragma unroll
        for (int dc = 0; dc < 4; dc++)
#pragma unroll
            for (int dd = 0; dd < 2; dd++)
                av[dc][dd] = *reinterpret_cast<const bf16x8*>(&Vc[voff[dc][dd]]);

        // ---- S^T = K * Q^T ----
        f32x4 st[4];
        __builtin_amdgcn_s_setprio(1);
#pragma unroll
        for (int c = 0; c < 4; c++) {
            st[c] = zero4;
#pragma unroll
            for (int dd = 0; dd < 2; dd++)
                st[c] = __builtin_amdgcn_mfma_f32_16x16x32_bf16(kf[c][dd], aq[dd], st[c], 0, 0, 0);
        }
        __builtin_amdgcn_s_setprio(0);

        if (kt == qt) {     // causal mask on diagonal tile
#pragma unroll
            for (int c = 0; c < 4; c++) {
                int kb = kt64 + ((c >> 1) << 5) + ((c & 1) << 2) + lg * 8;
#pragma unroll
                for (int jj = 0; jj < 4; jj++)
                    if (kb + jj > qr) st[c][jj] = -INFINITY;
            }
        }

        // ---- tile max: tree reduction (depth 4) ----
        float m0a = fmaxf(st[0][0], st[0][1]), m0b = fmaxf(st[0][2], st[0][3]);
        float m1a = fmaxf(st[1][0], st[1][1]), m1b = fmaxf(st[1][2], st[1][3]);
        float m2a = fmaxf(st[2][0], st[2][1]), m2b = fmaxf(st[2][2], st[2][3]);
        float m3a = fmaxf(st[3][0], st[3][1]), m3b = fmaxf(st[3][2], st[3][3]);
        float mx = fmaxf(fmaxf(fmaxf(m0a, m0b), fmaxf(m1a, m1b)),
                         fmaxf(fmaxf(m2a, m2b), fmaxf(m3a, m3b)));
        mx = fmaxf(mx, __shfl_xor(mx, 16));
        mx = fmaxf(mx, __shfl_xor(mx, 32));

        // ---- defer-max: rescale only when the max grew past THR=8 (log2 domain) ----
        if (__any(mx - mr > 8.f)) {
            float mnew = fmaxf(mr, mx);
            float scl = exp2f(mr - mnew);
            mr = mnew;
            lr *= scl;
#pragma unroll
            for (int dc = 0; dc < 4; dc++)
#pragma unroll
                for (int jj = 0; jj < 4; jj++) o[dc][jj] *= scl;
        }

        // ---- P = exp2(S - mr), row-sum (tree), pack to bf16 ----
        f32x4 rv0, rv1;
#pragma unroll
        for (int c = 0; c < 4; c++)
#pragma unroll
            for (int jj = 0; jj < 4; jj++)
                st[c][jj] = exp2f(st[c][jj] - mr);
#pragma unroll
        for (int jj = 0; jj < 4; jj++) {
            rv0[jj] = st[0][jj] + st[1][jj];
            rv1[jj] = st[2][jj] + st[3][jj];
        }
        float rs = ((rv0[0] + rv0[1]) + (rv0[2] + rv0[3])) +
                   ((rv1[0] + rv1[1]) + (rv1[2] + rv1[3]));
        rs += __shfl_xor(rs, 16);
        rs += __shfl_xor(rs, 32);
        lr += rs;

        union { bf16x8 v; unsigned int u[4]; } pf0, pf1;
        pf0.u[0] = pkbf(st[0][0], st[0][1]);
        pf0.u[1] = pkbf(st[0][2], st[0][3]);
        pf0.u[2] = pkbf(st[1][0], st[1][1]);
        pf0.u[3] = pkbf(st[1][2], st[1][3]);
        pf1.u[0] = pkbf(st[2][0], st[2][1]);
        pf1.u[1] = pkbf(st[2][2], st[2][3]);
        pf1.u[2] = pkbf(st[3][0], st[3][1]);
        pf1.u[3] = pkbf(st[3][2], st[3][3]);

        // ---- O^T += V^T P ----
        __builtin_amdgcn_s_setprio(1);
#pragma unroll
        for (int dc = 0; dc < 4; dc++) {
            o[dc] = __builtin_amdgcn_mfma_f32_16x16x32_bf16(av[dc][0], pf0.v, o[dc], 0, 0, 0);
            o[dc] = __builtin_amdgcn_mfma_f32_16x16x32_bf16(av[dc][1], pf1.v, o[dc], 0, 0, 0);
        }
        __builtin_amdgcn_s_setprio(0);

        if (hn) {   // write-late into the other buffer
            ushort* Kn = Kbuf[cur ^ 1];
            ushort* Vn = Vbuf[cur ^ 1];
            *reinterpret_cast<uint4*>(&Kn[w0]) = nk0;
            *reinterpret_cast<uint4*>(&Kn[w1]) = nk1;
            *reinterpret_cast<uint4*>(&Vn[w0]) = nv0;
            *reinterpret_cast<uint4*>(&Vn[w1]) = nv1;
        }
        __syncthreads();
        cur ^= 1;
    }

    // epilogue: lane holds o^T[d = dc*16 + lg*4 + jj][q = l15]
    const int b = bh >> 4, h = bh & 15;
    float inv = 1.f / lr;
#pragma unroll
    for (int dc = 0; dc < 4; dc++) {
        ushort4 ov;
        ov.x = bf_bits(o[dc][0] * inv);
        ov.y = bf_bits(o[dc][1] * inv);
        ov.z = bf_bits(o[dc][2] * inv);
        ov.w = bf_bits(o[dc][3] * inv);
        *reinterpret_cast<ushort4*>(
            &y[(size_t)(b * T_SEQ + qr) * C_DIM + h * 64 + dc * 16 + lg * 4]) = ov;
    }
}

// ---------------- LayerNorm over C=1024, one block per row ----------------
__global__ __launch_bounds__(256) void ln_kernel(const float* __restrict__ y2,
                                                 const float* __restrict__ wgt,
                                                 const float* __restrict__ bias,
                                                 float* __restrict__ out) {
    const int row = blockIdx.x;
    const int t = threadIdx.x;
    float4 v = reinterpret_cast<const float4*>(y2 + (size_t)row * C_DIM)[t];
    float s = v.x + v.y + v.z + v.w;
    float s2 = v.x * v.x + v.y * v.y + v.z * v.z + v.w * v.w;
#pragma unroll
    for (int d = 1; d < 64; d <<= 1) {
        s += __shfl_xor(s, d);
        s2 += __shfl_xor(s2, d);
    }
    __shared__ float ps[4], ps2[4];
    const int lane = t & 63, w = t >> 6;
    if (lane == 0) { ps[w] = s; ps2[w] = s2; }
    __syncthreads();
    s = ps[0] + ps[1] + ps[2] + ps[3];
    s2 = ps2[0] + ps2[1] + ps2[2] + ps2[3];
    float mean = s * (1.f / C_DIM);
    float var = s2 * (1.f / C_DIM) - mean * mean;
    float inv = rsqrtf(var + 1e-5f);
    float4 wv = reinterpret_cast<const float4*>(wgt)[t];
    float4 bv = reinterpret_cast<const float4*>(bias)[t];
    float4 ov;
    ov.x = (v.x - mean) * inv * wv.x + bv.x;
    ov.y = (v.y - mean) * inv * wv.y + bv.y;
    ov.z = (v.z - mean) * inv * wv.z + bv.z;
    ov.w = (v.w - mean) * inv * wv.w + bv.w;
    reinterpret_cast<float4*>(out + (size_t)row * C_DIM)[t] = ov;
}

extern "C" void kernel_launch(void* const* d_in, const int* in_sizes, int n_in,
                              void* d_out, int out_size, void* d_ws, size_t ws_size,
                              hipStream_t stream) {
    const float* x      = (const float*)d_in[0];
    const float* freqs  = (const float*)d_in[1];
    const float* W_attn = (const float*)d_in[2];
    const float* W_proj = (const float*)d_in[3];
    const float* lnw    = (const float*)d_in[4];
    const float* lnb    = (const float*)d_in[5];
    float* out = (float*)d_out;
    char* ws = (char*)d_ws;

    __hip_bfloat16* xb   = (__hip_bfloat16*)(ws);                 // 8.4 MB
    __hip_bfloat16* Wab  = (__hip_bfloat16*)(ws + 8388608);       // 6.3 MB
    __hip_bfloat16* Wpb  = (__hip_bfloat16*)(ws + 14680064);      // 2.1 MB
    __hip_bfloat16* qkvb = (__hip_bfloat16*)(ws + 16777216);      // 25.2 MB
    __hip_bfloat16* q_s  = (__hip_bfloat16*)(ws + 41943040);      // 8.4 MB
    __hip_bfloat16* k_s  = (__hip_bfloat16*)(ws + 50331648);      // 8.4 MB
    __hip_bfloat16* v_t  = (__hip_bfloat16*)(ws + 58720256);      // 8.4 MB (B,H,D,T)
    __hip_bfloat16* y_at = (__hip_bfloat16*)(ws + 67108864);      // 8.4 MB
    float*          y2   = (float*)(ws + 75497472);               // 16.8 MB

    // casts
    cast_f32_bf16<<<(BT * C_DIM / 4) / 256, 256, 0, stream>>>(x, xb, BT * C_DIM / 4);
    cast_f32_bf16<<<(C3 * C_DIM / 4) / 256, 256, 0, stream>>>(W_attn, Wab, C3 * C_DIM / 4);
    cast_f32_bf16<<<(C_DIM * C_DIM / 4) / 256, 256, 0, stream>>>(W_proj, Wpb, C_DIM * C_DIM / 4);

    // qkv = x @ W_attn^T
    gemm_bt<1><<<dim3(C3 / 128, BT / 128), 256, 0, stream>>>(xb, Wab, qkvb, BT, C3, C_DIM);

    // rope q,k + transpose v
    rope_qk<<<(BT * H_HEADS * 32) / 256, 256, 0, stream>>>(qkvb, freqs, q_s, k_s);
    transpose_v<<<dim3(T_SEQ / 64, BH), 256, 0, stream>>>(qkvb, v_t);

    // attention: 1024 blocks (32 q-tiles x 32 heads), LPT order
    attn_kernel<<<1024, 256, 0, stream>>>(q_s, k_s, v_t, y_at);

    // proj
    gemm_bt<0><<<dim3(C_DIM / 128, BT / 128), 256, 0, stream>>>(y_at, Wpb, y2, BT, C_DIM, C_DIM);

    // layernorm
    ln_kernel<<<BT, 256, 0, stream>>>(y2, lnw, lnb, out);
}

// Round 5
// 135.266 us; speedup vs baseline: 2.3317x; 1.1202x over previous
//
#include <hip/hip_runtime.h>
#include <hip/hip_bf16.h>
#include <math.h>

typedef short bf16x8 __attribute__((ext_vector_type(8)));
typedef float f32x4 __attribute__((ext_vector_type(4)));

#define T_SEQ 2048
#define C_DIM 1024
#define H_HEADS 16
#define D_HEAD 64
#define BT 4096          // B*T
#define C3 3072
#define BH 32            // B*H

static __device__ inline unsigned short bf_bits(float f) {
    __hip_bfloat16 h = __float2bfloat16(f);
    unsigned short u;
    __builtin_memcpy(&u, &h, 2);
    return u;
}

static __device__ inline unsigned int pkbf(float a, float b) {
    return (unsigned int)bf_bits(a) | ((unsigned int)bf_bits(b) << 16);
}

__device__ __forceinline__ void gload16(const void* g, void* l) {
    __builtin_amdgcn_global_load_lds(
        (const __attribute__((address_space(1))) void*)g,
        (__attribute__((address_space(3))) void*)l, 16, 0, 0);
}

// LDS XOR swizzle (element units, 8-elem granule): spreads rows across bank quads
__device__ __forceinline__ int swz(int r) {
    return ((((r & 3) ^ ((r >> 3) & 3)) | (((r >> 3) & 1) << 2)) << 3);
}

// ---------------- cast f32 -> bf16, 4 elems/thread ----------------
__global__ void cast_f32_bf16(const float* __restrict__ in,
                              __hip_bfloat16* __restrict__ out, int n4) {
    int i = blockIdx.x * blockDim.x + threadIdx.x;
    if (i >= n4) return;
    float4 v = reinterpret_cast<const float4*>(in)[i];
    ushort4 o;
    o.x = bf_bits(v.x); o.y = bf_bits(v.y); o.z = bf_bits(v.z); o.w = bf_bits(v.w);
    reinterpret_cast<ushort4*>(out)[i] = o;
}

// ---------------- GEMM: Cout = A(M,K) * Bw(N,K)^T, bf16 MFMA ----------------
// 128x128 tile, BK=64, 4 waves. Double-buffered global_load_lds pipeline
// (issue-early: stage tile t+1 before computing tile t; one barrier/iter).
// LDS dest linear (gload_lds requirement); global source column pre-swizzled,
// reads XOR the same involution -> conflict-free ds_read_b128.
template<int OUT_BF16>
__global__ __launch_bounds__(256) void gemm_bt(
    const __hip_bfloat16* __restrict__ A,
    const __hip_bfloat16* __restrict__ Bw,
    void* __restrict__ Cout, int M, int N, int K) {
    __shared__ __hip_bfloat16 As[2][128][64];
    __shared__ __hip_bfloat16 Bs[2][128][64];
    const int t = threadIdx.x;
    const int lane = t & 63, w = t >> 6;
    const int wr = w >> 1, wc = w & 1;
    const int l15 = lane & 15, lg = lane >> 4;
    const int m0 = blockIdx.y * 128, n0 = blockIdx.x * 128;

    const int srow = lane >> 3;                   // 0..7 (row within 8-row stripe)
    const int scol = ((lane & 7) ^ srow) * 8;     // pre-swizzled global col granule
    const int xr = (l15 & 7) << 3;                // read-side XOR (element units)

    f32x4 acc[4][4];
    f32x4 zero4 = {0.f, 0.f, 0.f, 0.f};
#pragma unroll
    for (int m = 0; m < 4; m++)
#pragma unroll
        for (int n = 0; n < 4; n++) acc[m][n] = zero4;

    auto stage = [&](int buf, int k0) {
#pragma unroll
        for (int i = 0; i < 4; i++) {
            int rbase = w * 32 + i * 8;
            gload16(&A[(size_t)(m0 + rbase + srow) * K + k0 + scol], &As[buf][rbase][0]);
            gload16(&Bw[(size_t)(n0 + rbase + srow) * K + k0 + scol], &Bs[buf][rbase][0]);
        }
    };

    const int nt = K >> 6;
    stage(0, 0);
    __syncthreads();        // drains vmcnt(0): buf0 ready

    for (int tk = 0; tk < nt; tk++) {
        const int cur = tk & 1;
        if (tk + 1 < nt) stage(cur ^ 1, (tk + 1) << 6);   // issue-early, overlaps compute
#pragma unroll
        for (int kk = 0; kk < 2; kk++) {
            bf16x8 a[4], b[4];
            const int co = (kk * 32 + lg * 8) ^ xr;
#pragma unroll
            for (int m = 0; m < 4; m++)
                a[m] = *reinterpret_cast<const bf16x8*>(&As[cur][wr * 64 + m * 16 + l15][co]);
#pragma unroll
            for (int n = 0; n < 4; n++)
                b[n] = *reinterpret_cast<const bf16x8*>(&Bs[cur][wc * 64 + n * 16 + l15][co]);
            __builtin_amdgcn_s_setprio(1);
#pragma unroll
            for (int m = 0; m < 4; m++)
#pragma unroll
                for (int n = 0; n < 4; n++)
                    acc[m][n] = __builtin_amdgcn_mfma_f32_16x16x32_bf16(a[m], b[n], acc[m][n], 0, 0, 0);
            __builtin_amdgcn_s_setprio(0);
        }
        __syncthreads();    // stage(t+1) done + all reads of buf[cur] done
    }

#pragma unroll
    for (int m = 0; m < 4; m++)
#pragma unroll
        for (int n = 0; n < 4; n++)
#pragma unroll
            for (int jj = 0; jj < 4; jj++) {
                int row = m0 + wr * 64 + m * 16 + lg * 4 + jj;
                int col = n0 + wc * 64 + n * 16 + l15;
                float v = acc[m][n][jj];
                if (OUT_BF16)
                    ((__hip_bfloat16*)Cout)[(size_t)row * N + col] = __float2bfloat16(v);
                else
                    ((float*)Cout)[(size_t)row * N + col] = v;
            }
}

// ---------------- RoPE for q,k -> (B,H,T,D); q pre-scaled by 0.125*log2(e) ----------------
__global__ void rope_qk(const __hip_bfloat16* __restrict__ qkv,
                        const float* __restrict__ freqs,
                        __hip_bfloat16* __restrict__ q_s,
                        __hip_bfloat16* __restrict__ k_s) {
    int idx = blockIdx.x * 256 + threadIdx.x;   // BT*H*32 threads
    int i = idx & 31;
    int h = (idx >> 5) & 15;
    int bt = idx >> 9;
    int b = bt >> 11;           // T=2048
    int tp = bt & 2047;
    float th = (float)tp * freqs[i];
    float sn = sinf(th), cs = cosf(th);
    size_t qoff = (size_t)bt * C3 + h * 64;
    float q1 = __bfloat162float(qkv[qoff + 2 * i]);
    float q2 = __bfloat162float(qkv[qoff + 2 * i + 1]);
    float k1 = __bfloat162float(qkv[qoff + C_DIM + 2 * i]);
    float k2 = __bfloat162float(qkv[qoff + C_DIM + 2 * i + 1]);
    size_t obase = ((size_t)(b * H_HEADS + h) * T_SEQ + tp) * D_HEAD;
    const float sc = 0.125f * 1.44269504f;      // 1/sqrt(D) * log2(e)
    q_s[obase + i]      = __float2bfloat16((q1 * cs - q2 * sn) * sc);
    q_s[obase + 32 + i] = __float2bfloat16((q1 * sn + q2 * cs) * sc);
    k_s[obase + i]      = __float2bfloat16(k1 * cs - k2 * sn);
    k_s[obase + 32 + i] = __float2bfloat16(k1 * sn + k2 * cs);
}

// ---------------- V transpose: qkv v-part -> v_t (B,H,D,T) ----------------
__global__ __launch_bounds__(256) void transpose_v(const __hip_bfloat16* __restrict__ qkv,
                                                   __hip_bfloat16* __restrict__ v_t) {
    __shared__ __hip_bfloat16 tile[64][72];
    const int bh = blockIdx.y, tt = blockIdx.x;
    const int b = bh >> 4, h = bh & 15;
    const int t = threadIdx.x;
    const int r = t >> 2, c0 = (t & 3) * 16;
    const __hip_bfloat16* src = qkv + (size_t)(b * T_SEQ + tt * 64 + r) * C3 + 2 * C_DIM + h * 64 + c0;
    uint4 v0 = reinterpret_cast<const uint4*>(src)[0];
    uint4 v1 = reinterpret_cast<const uint4*>(src)[1];
    *reinterpret_cast<uint4*>(&tile[r][c0]) = v0;
    *reinterpret_cast<uint4*>(&tile[r][c0 + 8]) = v1;
    __syncthreads();
    const int d = t >> 2;
    ushort out[16];
#pragma unroll
    for (int i = 0; i < 16; i++) {
        __hip_bfloat16 x = tile[c0 + i][d];
        __builtin_memcpy(&out[i], &x, 2);
    }
    __hip_bfloat16* dst = v_t + (size_t)bh * D_HEAD * T_SEQ + (size_t)d * T_SEQ + tt * 64 + c0;
    reinterpret_cast<uint4*>(dst)[0] = *reinterpret_cast<uint4*>(&out[0]);
    reinterpret_cast<uint4*>(dst)[1] = *reinterpret_cast<uint4*>(&out[8]);
}

// ---------------- flash attention ----------------
// Block = (head bh, 64-row q tile); 1024 blocks. Swapped QK^T, in-register P,
// LDS K/V^T double-buffered issue-early/write-late, defer-max, tree reductions.
__global__ __launch_bounds__(256, 4) void attn_kernel(
    const __hip_bfloat16* __restrict__ q_s,
    const __hip_bfloat16* __restrict__ k_s,
    const __hip_bfloat16* __restrict__ v_t,
    __hip_bfloat16* __restrict__ y) {
    __shared__ ushort Kbuf[2][64 * 64];
    __shared__ ushort Vbuf[2][64 * 64];

    const int bid = blockIdx.x;                 // 1024 blocks
    const int qt = 31 - (bid >> 5);             // LPT: longest first
    const int bh = bid & 31;                    // bh%8 -> head-per-XCD L2 locality
    const int t = threadIdx.x, lane = t & 63, w = t >> 6;
    const int l15 = lane & 15, lg = lane >> 4;
    const size_t hbase = (size_t)bh * T_SEQ * D_HEAD;
    const int qbase = qt * 64;
    const int qr = qbase + w * 16 + l15;

    // Q fragment
    bf16x8 aq[2];
#pragma unroll
    for (int dd = 0; dd < 2; dd++)
        aq[dd] = *reinterpret_cast<const bf16x8*>(&q_s[hbase + (size_t)qr * 64 + dd * 32 + lg * 8]);

    f32x4 zero4 = {0.f, 0.f, 0.f, 0.f};
    f32x4 o[4];
#pragma unroll
    for (int dc = 0; dc < 4; dc++) o[dc] = zero4;
    float mr = -INFINITY, lr = 0.f;

    // LDS read offsets (element units), hoisted
    int koff[4][2], voff[4][2];
#pragma unroll
    for (int c = 0; c < 4; c++) {
        int kro = ((c >> 1) << 5) + ((c & 1) << 2) + ((l15 >> 2) << 3) + (l15 & 3);
        int sz = swz(kro);
#pragma unroll
        for (int dd = 0; dd < 2; dd++)
            koff[c][dd] = kro * 64 + ((dd * 32 + lg * 8) ^ sz);
    }
#pragma unroll
    for (int dc = 0; dc < 4; dc++) {
        int vro = dc * 16 + l15;
        int sz = swz(vro);
#pragma unroll
        for (int dd = 0; dd < 2; dd++)
            voff[dc][dd] = vro * 64 + ((dd * 32 + lg * 8) ^ sz);
    }

    // staging geometry
    const int ssr = t >> 2;                 // tile row 0..63
    const int sse = (t & 3) * 16;           // elem col {0,16,32,48}
    const int sw = swz(ssr);
    const int w0 = ssr * 64 + (sse ^ sw);
    const int w1 = ssr * 64 + ((sse + 8) ^ sw);

    int cur = 0;

    // prologue: stage tile 0
    {
        const __hip_bfloat16* kg = k_s + hbase + (size_t)ssr * 64 + sse;
        uint4 a0 = reinterpret_cast<const uint4*>(kg)[0];
        uint4 a1 = reinterpret_cast<const uint4*>(kg)[1];
        const __hip_bfloat16* vg = v_t + hbase + (size_t)ssr * T_SEQ + sse;
        uint4 b0 = reinterpret_cast<const uint4*>(vg)[0];
        uint4 b1 = reinterpret_cast<const uint4*>(vg)[1];
        *reinterpret_cast<uint4*>(&Kbuf[0][w0]) = a0;
        *reinterpret_cast<uint4*>(&Kbuf[0][w1]) = a1;
        *reinterpret_cast<uint4*>(&Vbuf[0][w0]) = b0;
        *reinterpret_cast<uint4*>(&Vbuf[0][w1]) = b1;
    }
    __syncthreads();

    for (int kt = 0; kt <= qt; kt++) {
        const int kt64 = kt << 6;
        const bool hn = kt < qt;
        uint4 nk0, nk1, nv0, nv1;
        if (hn) {   // issue next-tile loads early (latency hides under compute)
            const __hip_bfloat16* kg = k_s + hbase + (size_t)(kt64 + 64 + ssr) * 64 + sse;
            nk0 = reinterpret_cast<const uint4*>(kg)[0];
            nk1 = reinterpret_cast<const uint4*>(kg)[1];
            const __hip_bfloat16* vg = v_t + hbase + (size_t)ssr * T_SEQ + kt64 + 64 + sse;
            nv0 = reinterpret_cast<const uint4*>(vg)[0];
            nv1 = reinterpret_cast<const uint4*>(vg)[1];
        }
        const ushort* Kc = Kbuf[cur];
        const ushort* Vc = Vbuf[cur];
        bf16x8 kf[4][2], av[4][2];
#pragma unroll
        for (int c = 0; c < 4; c++)
#pragma unroll
            for (int dd = 0; dd < 2; dd++)
                kf[c][dd] = *reinterpret_cast<const bf16x8*>(&Kc[koff[c][dd]]);
#pragma unroll
        for (int dc = 0; dc < 4; dc++)
#pragma unroll
            for (int dd = 0; dd < 2; dd++)
                av[dc][dd] = *reinterpret_cast<const bf16x8*>(&Vc[voff[dc][dd]]);

        // ---- S^T = K * Q^T ----
        f32x4 st[4];
        __builtin_amdgcn_s_setprio(1);
#pragma unroll
        for (int c = 0; c < 4; c++) {
            st[c] = zero4;
#pragma unroll
            for (int dd = 0; dd < 2; dd++)
                st[c] = __builtin_amdgcn_mfma_f32_16x16x32_bf16(kf[c][dd], aq[dd], st[c], 0, 0, 0);
        }
        __builtin_amdgcn_s_setprio(0);

        if (kt == qt) {     // causal mask on diagonal tile
#pragma unroll
            for (int c = 0; c < 4; c++) {
                int kb = kt64 + ((c >> 1) << 5) + ((c & 1) << 2) + lg * 8;
#pragma unroll
                for (int jj = 0; jj < 4; jj++)
                    if (kb + jj > qr) st[c][jj] = -INFINITY;
            }
        }

        // ---- tile max: tree reduction (depth 4) ----
        float m0a = fmaxf(st[0][0], st[0][1]), m0b = fmaxf(st[0][2], st[0][3]);
        float m1a = fmaxf(st[1][0], st[1][1]), m1b = fmaxf(st[1][2], st[1][3]);
        float m2a = fmaxf(st[2][0], st[2][1]), m2b = fmaxf(st[2][2], st[2][3]);
        float m3a = fmaxf(st[3][0], st[3][1]), m3b = fmaxf(st[3][2], st[3][3]);
        float mx = fmaxf(fmaxf(fmaxf(m0a, m0b), fmaxf(m1a, m1b)),
                         fmaxf(fmaxf(m2a, m2b), fmaxf(m3a, m3b)));
        mx = fmaxf(mx, __shfl_xor(mx, 16));
        mx = fmaxf(mx, __shfl_xor(mx, 32));

        // ---- defer-max: rescale only when the max grew past THR=8 (log2 domain) ----
        if (__any(mx - mr > 8.f)) {
            float mnew = fmaxf(mr, mx);
            float scl = exp2f(mr - mnew);
            mr = mnew;
            lr *= scl;
#pragma unroll
            for (int dc = 0; dc < 4; dc++)
#pragma unroll
                for (int jj = 0; jj < 4; jj++) o[dc][jj] *= scl;
        }

        // ---- P = exp2(S - mr), row-sum (tree), pack to bf16 ----
        f32x4 rv0, rv1;
#pragma unroll
        for (int c = 0; c < 4; c++)
#pragma unroll
            for (int jj = 0; jj < 4; jj++)
                st[c][jj] = exp2f(st[c][jj] - mr);
#pragma unroll
        for (int jj = 0; jj < 4; jj++) {
            rv0[jj] = st[0][jj] + st[1][jj];
            rv1[jj] = st[2][jj] + st[3][jj];
        }
        float rs = ((rv0[0] + rv0[1]) + (rv0[2] + rv0[3])) +
                   ((rv1[0] + rv1[1]) + (rv1[2] + rv1[3]));
        rs += __shfl_xor(rs, 16);
        rs += __shfl_xor(rs, 32);
        lr += rs;

        union { bf16x8 v; unsigned int u[4]; } pf0, pf1;
        pf0.u[0] = pkbf(st[0][0], st[0][1]);
        pf0.u[1] = pkbf(st[0][2], st[0][3]);
        pf0.u[2] = pkbf(st[1][0], st[1][1]);
        pf0.u[3] = pkbf(st[1][2], st[1][3]);
        pf1.u[0] = pkbf(st[2][0], st[2][1]);
        pf1.u[1] = pkbf(st[2][2], st[2][3]);
        pf1.u[2] = pkbf(st[3][0], st[3][1]);
        pf1.u[3] = pkbf(st[3][2], st[3][3]);

        // ---- O^T += V^T P ----
        __builtin_amdgcn_s_setprio(1);
#pragma unroll
        for (int dc = 0; dc < 4; dc++) {
            o[dc] = __builtin_amdgcn_mfma_f32_16x16x32_bf16(av[dc][0], pf0.v, o[dc], 0, 0, 0);
            o[dc] = __builtin_amdgcn_mfma_f32_16x16x32_bf16(av[dc][1], pf1.v, o[dc], 0, 0, 0);
        }
        __builtin_amdgcn_s_setprio(0);

        if (hn) {   // write-late into the other buffer
            ushort* Kn = Kbuf[cur ^ 1];
            ushort* Vn = Vbuf[cur ^ 1];
            *reinterpret_cast<uint4*>(&Kn[w0]) = nk0;
            *reinterpret_cast<uint4*>(&Kn[w1]) = nk1;
            *reinterpret_cast<uint4*>(&Vn[w0]) = nv0;
            *reinterpret_cast<uint4*>(&Vn[w1]) = nv1;
        }
        __syncthreads();
        cur ^= 1;
    }

    // epilogue: lane holds o^T[d = dc*16 + lg*4 + jj][q = l15]
    const int b = bh >> 4, h = bh & 15;
    float inv = 1.f / lr;
#pragma unroll
    for (int dc = 0; dc < 4; dc++) {
        ushort4 ov;
        ov.x = bf_bits(o[dc][0] * inv);
        ov.y = bf_bits(o[dc][1] * inv);
        ov.z = bf_bits(o[dc][2] * inv);
        ov.w = bf_bits(o[dc][3] * inv);
        *reinterpret_cast<ushort4*>(
            &y[(size_t)(b * T_SEQ + qr) * C_DIM + h * 64 + dc * 16 + lg * 4]) = ov;
    }
}

// ---------------- LayerNorm over C=1024, one block per row ----------------
__global__ __launch_bounds__(256) void ln_kernel(const float* __restrict__ y2,
                                                 const float* __restrict__ wgt,
                                                 const float* __restrict__ bias,
                                                 float* __restrict__ out) {
    const int row = blockIdx.x;
    const int t = threadIdx.x;
    float4 v = reinterpret_cast<const float4*>(y2 + (size_t)row * C_DIM)[t];
    float s = v.x + v.y + v.z + v.w;
    float s2 = v.x * v.x + v.y * v.y + v.z * v.z + v.w * v.w;
#pragma unroll
    for (int d = 1; d < 64; d <<= 1) {
        s += __shfl_xor(s, d);
        s2 += __shfl_xor(s2, d);
    }
    __shared__ float ps[4], ps2[4];
    const int lane = t & 63, w = t >> 6;
    if (lane == 0) { ps[w] = s; ps2[w] = s2; }
    __syncthreads();
    s = ps[0] + ps[1] + ps[2] + ps[3];
    s2 = ps2[0] + ps2[1] + ps2[2] + ps2[3];
    float mean = s * (1.f / C_DIM);
    float var = s2 * (1.f / C_DIM) - mean * mean;
    float inv = rsqrtf(var + 1e-5f);
    float4 wv = reinterpret_cast<const float4*>(wgt)[t];
    float4 bv = reinterpret_cast<const float4*>(bias)[t];
    float4 ov;
    ov.x = (v.x - mean) * inv * wv.x + bv.x;
    ov.y = (v.y - mean) * inv * wv.y + bv.y;
    ov.z = (v.z - mean) * inv * wv.z + bv.z;
    ov.w = (v.w - mean) * inv * wv.w + bv.w;
    reinterpret_cast<float4*>(out + (size_t)row * C_DIM)[t] = ov;
}

extern "C" void kernel_launch(void* const* d_in, const int* in_sizes, int n_in,
                              void* d_out, int out_size, void* d_ws, size_t ws_size,
                              hipStream_t stream) {
    const float* x      = (const float*)d_in[0];
    const float* freqs  = (const float*)d_in[1];
    const float* W_attn = (const float*)d_in[2];
    const float* W_proj = (const float*)d_in[3];
    const float* lnw    = (const float*)d_in[4];
    const float* lnb    = (const float*)d_in[5];
    float* out = (float*)d_out;
    char* ws = (char*)d_ws;

    __hip_bfloat16* xb   = (__hip_bfloat16*)(ws);                 // 8.4 MB
    __hip_bfloat16* Wab  = (__hip_bfloat16*)(ws + 8388608);       // 6.3 MB
    __hip_bfloat16* Wpb  = (__hip_bfloat16*)(ws + 14680064);      // 2.1 MB
    __hip_bfloat16* qkvb = (__hip_bfloat16*)(ws + 16777216);      // 25.2 MB
    __hip_bfloat16* q_s  = (__hip_bfloat16*)(ws + 41943040);      // 8.4 MB
    __hip_bfloat16* k_s  = (__hip_bfloat16*)(ws + 50331648);      // 8.4 MB
    __hip_bfloat16* v_t  = (__hip_bfloat16*)(ws + 58720256);      // 8.4 MB (B,H,D,T)
    __hip_bfloat16* y_at = (__hip_bfloat16*)(ws + 67108864);      // 8.4 MB
    float*          y2   = (float*)(ws + 75497472);               // 16.8 MB

    // casts
    cast_f32_bf16<<<(BT * C_DIM / 4) / 256, 256, 0, stream>>>(x, xb, BT * C_DIM / 4);
    cast_f32_bf16<<<(C3 * C_DIM / 4) / 256, 256, 0, stream>>>(W_attn, Wab, C3 * C_DIM / 4);
    cast_f32_bf16<<<(C_DIM * C_DIM / 4) / 256, 256, 0, stream>>>(W_proj, Wpb, C_DIM * C_DIM / 4);

    // qkv = x @ W_attn^T
    gemm_bt<1><<<dim3(C3 / 128, BT / 128), 256, 0, stream>>>(xb, Wab, qkvb, BT, C3, C_DIM);

    // rope q,k + transpose v
    rope_qk<<<(BT * H_HEADS * 32) / 256, 256, 0, stream>>>(qkvb, freqs, q_s, k_s);
    transpose_v<<<dim3(T_SEQ / 64, BH), 256, 0, stream>>>(qkvb, v_t);

    // attention: 1024 blocks (32 q-tiles x 32 heads), LPT order
    attn_kernel<<<1024, 256, 0, stream>>>(q_s, k_s, v_t, y_at);

    // proj
    gemm_bt<0><<<dim3(C_DIM / 128, BT / 128), 256, 0, stream>>>(y_at, Wpb, y2, BT, C_DIM, C_DIM);

    // layernorm
    ln_kernel<<<BT, 256, 0, stream>>>(y2, lnw, lnb, out);
}